// Round 1
// baseline (312.351 us; speedup 1.0000x reference)
//
#include <hip/hip_runtime.h>

#define NT 16384
#define NH 2048
#define NE 64
#define TOPK 8
#define T_TILE 32
#define KT 32
#define XPAD 36
#define WPAD 36
#define LPAD 68

// output layout (floats)
#define LOFF 0
#define WOFF (NT * NE)                    // 1048576
#define IOFF (WOFF + NT * TOPK)           // 1179648
#define MOFF (IOFF + NT * TOPK)           // 1310720

__global__ __launch_bounds__(256, 2)
void router_kernel(const float* __restrict__ X, const float* __restrict__ Wg,
                   const float* __restrict__ bg, float* __restrict__ out) {
    __shared__ float Xs[T_TILE][XPAD];
    __shared__ float Ws[NE][WPAD];
    __shared__ float Ls[T_TILE][LPAD];

    const int tid   = threadIdx.x;
    const int tbase = blockIdx.x * T_TILE;

    // compute mapping: eg = tid>>4 (experts e0..e0+3), tg = tid&15 (tokens t0,t0+1)
    const int e0 = (tid >> 4) * 4;
    const int t0 = (tid & 15) * 2;

    // staging mapping: 8 lanes per row (128B contiguous per row segment)
    const int srow = tid >> 3;   // 0..31
    const int scol = (tid & 7) * 4;

    float acc[2][4];
#pragma unroll
    for (int j = 0; j < 2; j++)
#pragma unroll
        for (int i = 0; i < 4; i++) acc[j][i] = 0.0f;

    for (int kk = 0; kk < NH; kk += KT) {
        // stage X tile: 32 rows x 32 cols
        float4 xv = *(const float4*)(X + (size_t)(tbase + srow) * NH + kk + scol);
        // stage W tile: 64 rows x 32 cols (two rows per thread)
        float4 w0 = *(const float4*)(Wg + (size_t)srow * NH + kk + scol);
        float4 w1 = *(const float4*)(Wg + (size_t)(srow + 32) * NH + kk + scol);
        *(float4*)(&Xs[srow][scol])      = xv;
        *(float4*)(&Ws[srow][scol])      = w0;
        *(float4*)(&Ws[srow + 32][scol]) = w1;
        __syncthreads();

#pragma unroll
        for (int q = 0; q < KT / 4; q++) {
            float4 xr[2], wr[4];
#pragma unroll
            for (int j = 0; j < 2; j++) xr[j] = *(const float4*)(&Xs[t0 + j][q * 4]);
#pragma unroll
            for (int i = 0; i < 4; i++) wr[i] = *(const float4*)(&Ws[e0 + i][q * 4]);
#pragma unroll
            for (int j = 0; j < 2; j++)
#pragma unroll
                for (int i = 0; i < 4; i++) {
                    acc[j][i] = fmaf(xr[j].x, wr[i].x, acc[j][i]);
                    acc[j][i] = fmaf(xr[j].y, wr[i].y, acc[j][i]);
                    acc[j][i] = fmaf(xr[j].z, wr[i].z, acc[j][i]);
                    acc[j][i] = fmaf(xr[j].w, wr[i].w, acc[j][i]);
                }
        }
        __syncthreads();
    }

    // epilogue: add bias, stash logits tile in LDS
#pragma unroll
    for (int j = 0; j < 2; j++)
#pragma unroll
        for (int i = 0; i < 4; i++)
            Ls[t0 + j][e0 + i] = acc[j][i] + bg[e0 + i];
    __syncthreads();

    // coalesced logits write: 32x64 floats = 512 float4, 2 per thread
#pragma unroll
    for (int v = 0; v < 2; v++) {
        int f4 = tid + v * 256;          // 0..511
        int t  = f4 >> 4;
        int c  = (f4 & 15) * 4;
        float4 lv = *(const float4*)(&Ls[t][c]);
        *(float4*)(out + LOFF + (size_t)(tbase + t) * NE + c) = lv;
    }

    // top-8 + weights + indices + mask scatter: one thread per token
    if (tid < T_TILE) {
        const int t  = tid;
        const size_t gt = (size_t)(tbase + t);

        float m = -1e30f;
#pragma unroll
        for (int e = 0; e < NE; e++) m = fmaxf(m, Ls[t][e]);

        unsigned long long sel = 0ULL;
        int   idxs[TOPK];
        float vals[TOPK];
#pragma unroll
        for (int k = 0; k < TOPK; k++) {
            float best = -1e30f;
            int   bi   = 0;
            for (int e = 0; e < NE; e++) {
                if (!((sel >> e) & 1ULL)) {
                    float v = Ls[t][e];
                    if (v > best) { best = v; bi = e; }  // strict > : lowest index wins ties
                }
            }
            sel |= (1ULL << bi);
            idxs[k] = bi;
            vals[k] = best;
        }

        float ex[TOPK];
        float s = 0.0f;
#pragma unroll
        for (int k = 0; k < TOPK; k++) { ex[k] = __expf(vals[k] - m); s += ex[k]; }
        float inv = 1.0f / s;

#pragma unroll
        for (int k = 0; k < TOPK; k++) {
            out[WOFF + gt * TOPK + k] = ex[k] * inv;
            out[IOFF + gt * TOPK + k] = (float)idxs[k];
            out[MOFF + (size_t)idxs[k] * (TOPK * NT) + (size_t)k * NT + gt] = 1.0f;
        }
    }
}

extern "C" void kernel_launch(void* const* d_in, const int* in_sizes, int n_in,
                              void* d_out, int out_size, void* d_ws, size_t ws_size,
                              hipStream_t stream) {
    const float* X  = (const float*)d_in[0];
    const float* Wg = (const float*)d_in[1];
    const float* bg = (const float*)d_in[2];
    float* out = (float*)d_out;

    // zero the one-hot mask region (re-poisoned 0xAA before every launch)
    hipMemsetAsync(out + MOFF, 0, (size_t)NE * TOPK * NT * sizeof(float), stream);

    hipLaunchKernelGGL(router_kernel, dim3(NT / T_TILE), dim3(256), 0, stream,
                       X, Wg, bg, out);
}

// Round 2
// 281.246 us; speedup vs baseline: 1.1106x; 1.1106x over previous
//
#include <hip/hip_runtime.h>

#define NT 16384
#define NH 2048
#define NE 64
#define TOPK 8
#define TT 64           // tokens per block
#define KT 64           // k per staged tile
#define NTILES (NH / KT)

// output layout (floats)
#define LOFF 0
#define WOFF (NT * NE)
#define IOFF (WOFF + NT * TOPK)
#define MOFF (IOFF + NT * TOPK)

// bank swizzle: element [r][quad q] stored at quad (q ^ SWZ(r)); PAD=64 (none)
#define SWZ(r) (((r) + ((r) >> 3)) & 7)

typedef const __attribute__((address_space(1))) unsigned int* gptr_t;
typedef __attribute__((address_space(3))) unsigned int* lptr_t;

__global__ __launch_bounds__(256, 1)
void router_kernel(const float* __restrict__ X, const float* __restrict__ Wg,
                   const float* __restrict__ bg, float* __restrict__ out) {
    // [0,8192): X dbuf [2][64][64]; [8192,16384): W dbuf [2][64][64]
    // after GEMM loop, [0,12288) reused as P[3][64][64] k-split partials
    __shared__ float SBUF[16384];
    __shared__ float Ls[TT][NE + 1];   // pad 65: scalar col-reads 2-way max

    const int tid   = threadIdx.x;
    const int wave  = tid >> 6;        // = k-split id, 0..3
    const int lane  = tid & 63;
    const int eg    = lane >> 3;       // 0..7
    const int tg    = lane & 7;        // 0..7
    const int e0    = eg * 8;
    const int t0    = tg * 8;
    const int tbase = blockIdx.x * TT;

    // ---- staging geometry: call c covers slots c*256+tid (16B each) ----
    const int rb = tid >> 4;           // 0..15
    const int sq = tid & 15;
    const float* xsrc[4];
    const float* wsrc[4];
    int ldsx[4], ldsw[4];
#pragma unroll
    for (int c = 0; c < 4; c++) {
        int r  = c * 16 + rb;                       // row in tile (token / expert)
        int co = ((sq ^ SWZ(r)) << 2);              // swizzled source col (floats)
        xsrc[c] = X  + (size_t)(tbase + r) * NH + co;
        wsrc[c] = Wg + (size_t)r * NH + co;
        ldsx[c] = c * 1024 + wave * 256;            // float index, + buf*4096
        ldsw[c] = 8192 + c * 1024 + wave * 256;
    }

    float acc[8][8];
#pragma unroll
    for (int j = 0; j < 8; j++)
#pragma unroll
        for (int i = 0; i < 8; i++) acc[j][i] = 0.0f;

    // prefetch tile 0 -> buf 0
#pragma unroll
    for (int c = 0; c < 4; c++) {
        __builtin_amdgcn_global_load_lds((gptr_t)xsrc[c], (lptr_t)&SBUF[ldsx[c]], 16, 0, 0);
        __builtin_amdgcn_global_load_lds((gptr_t)wsrc[c], (lptr_t)&SBUF[ldsw[c]], 16, 0, 0);
    }

    int buf = 0;
    for (int kt = 0; kt < NTILES; kt++) {
        __syncthreads();   // drains my prefetch(kt); all waves joined => tile ready
        if (kt + 1 < NTILES) {
            const int nb = (buf ^ 1) * 4096;
            const size_t go = (size_t)(kt + 1) * KT;
#pragma unroll
            for (int c = 0; c < 4; c++) {
                __builtin_amdgcn_global_load_lds((gptr_t)(xsrc[c] + go), (lptr_t)&SBUF[nb + ldsx[c]], 16, 0, 0);
                __builtin_amdgcn_global_load_lds((gptr_t)(wsrc[c] + go), (lptr_t)&SBUF[nb + ldsw[c]], 16, 0, 0);
            }
        }
        const int bb = buf * 4096;
#pragma unroll
        for (int qq = 0; qq < 4; qq++) {
            const int q = (wave << 2) | qq;          // my k-quad, 0..15
            float4 xr[8], wr[8];
#pragma unroll
            for (int j = 0; j < 8; j++)
                xr[j] = *(const float4*)&SBUF[bb + (t0 + j) * 64 + ((q ^ ((tg + j) & 7)) << 2)];
#pragma unroll
            for (int i = 0; i < 8; i++)
                wr[i] = *(const float4*)&SBUF[bb + 8192 + (e0 + i) * 64 + ((q ^ ((eg + i) & 7)) << 2)];
#pragma unroll
            for (int j = 0; j < 8; j++)
#pragma unroll
                for (int i = 0; i < 8; i++) {
                    acc[j][i] = fmaf(xr[j].x, wr[i].x, acc[j][i]);
                    acc[j][i] = fmaf(xr[j].y, wr[i].y, acc[j][i]);
                    acc[j][i] = fmaf(xr[j].z, wr[i].z, acc[j][i]);
                    acc[j][i] = fmaf(xr[j].w, wr[i].w, acc[j][i]);
                }
        }
        buf ^= 1;
    }
    __syncthreads();   // all compute done; safe to overlay P onto stage buffers

    // ---- k-split reduction: waves 1..3 dump partials to P ----
    if (wave != 0) {
        const int pb = (wave - 1) * 4096;
#pragma unroll
        for (int j = 0; j < 8; j++) {
            float4 a0 = make_float4(acc[j][0], acc[j][1], acc[j][2], acc[j][3]);
            float4 a1 = make_float4(acc[j][4], acc[j][5], acc[j][6], acc[j][7]);
            *(float4*)&SBUF[pb + (t0 + j) * 64 + e0]     = a0;
            *(float4*)&SBUF[pb + (t0 + j) * 64 + e0 + 4] = a1;
        }
    }
    __syncthreads();

    if (wave == 0) {
        // reduce partials + bias, stage logits to Ls
#pragma unroll
        for (int s = 0; s < 3; s++)
#pragma unroll
            for (int j = 0; j < 8; j++) {
                float4 p0 = *(const float4*)&SBUF[s * 4096 + (t0 + j) * 64 + e0];
                float4 p1 = *(const float4*)&SBUF[s * 4096 + (t0 + j) * 64 + e0 + 4];
                acc[j][0] += p0.x; acc[j][1] += p0.y; acc[j][2] += p0.z; acc[j][3] += p0.w;
                acc[j][4] += p1.x; acc[j][5] += p1.y; acc[j][6] += p1.z; acc[j][7] += p1.w;
            }
        float4 b0 = *(const float4*)&bg[e0];
        float4 b1 = *(const float4*)&bg[e0 + 4];
        float bias[8] = {b0.x, b0.y, b0.z, b0.w, b1.x, b1.y, b1.z, b1.w};
#pragma unroll
        for (int j = 0; j < 8; j++)
#pragma unroll
            for (int i = 0; i < 8; i++)
                Ls[t0 + j][e0 + i] = acc[j][i] + bias[i];
    } else {
        // waves 1..3: zero this block's mask slab out[MOFF + seg*NT + tbase..+64)
        float4 z = make_float4(0.f, 0.f, 0.f, 0.f);
        for (int m = tid - 64; m < 8192; m += 192) {
            int seg = m >> 4;
            int off = (m & 15) << 2;
            *(float4*)(out + MOFF + (size_t)seg * NT + tbase + off) = z;
        }
    }
    __syncthreads();

    // ---- coalesced logits write from Ls (all 256 threads) ----
#pragma unroll
    for (int v = 0; v < 4; v++) {
        int f  = v * 256 + tid;           // 0..1023 float4s
        int t  = f >> 4;
        int c4 = (f & 15) << 2;
        float4 o = make_float4(Ls[t][c4], Ls[t][c4 + 1], Ls[t][c4 + 2], Ls[t][c4 + 3]);
        *(float4*)(out + LOFF + (size_t)(tbase + t) * NE + c4) = o;
    }

    // ---- per-token top-8 + weights + indices + mask scatter ----
    if (tid < TT) {
        const int t = tid;
        const size_t gt = (size_t)(tbase + t);

        float m = -1e30f;
#pragma unroll
        for (int e = 0; e < NE; e++) m = fmaxf(m, Ls[t][e]);

        unsigned long long sel = 0ULL;
        int   idxs[TOPK];
        float vals[TOPK];
#pragma unroll
        for (int k = 0; k < TOPK; k++) {
            float best = -1e30f;
            int   bi   = 0;
            for (int e = 0; e < NE; e++) {
                if (!((sel >> e) & 1ULL)) {
                    float v = Ls[t][e];
                    if (v > best) { best = v; bi = e; }   // strict >: lowest index wins ties
                }
            }
            sel |= (1ULL << bi);
            idxs[k] = bi;
            vals[k] = best;
        }

        float ex[TOPK];
        float s = 0.0f;
#pragma unroll
        for (int k = 0; k < TOPK; k++) { ex[k] = __expf(vals[k] - m); s += ex[k]; }
        float inv = 1.0f / s;

#pragma unroll
        for (int k = 0; k < TOPK; k++) {
            out[WOFF + gt * TOPK + k] = ex[k] * inv;
            out[IOFF + gt * TOPK + k] = (float)idxs[k];
            out[MOFF + (size_t)idxs[k] * (TOPK * NT) + (size_t)k * NT + gt] = 1.0f;
        }
    }
}

extern "C" void kernel_launch(void* const* d_in, const int* in_sizes, int n_in,
                              void* d_out, int out_size, void* d_ws, size_t ws_size,
                              hipStream_t stream) {
    const float* X  = (const float*)d_in[0];
    const float* Wg = (const float*)d_in[1];
    const float* bg = (const float*)d_in[2];
    float* out = (float*)d_out;

    // mask zeroing is fused into the kernel (each block zeroes its token slab)
    hipLaunchKernelGGL(router_kernel, dim3(NT / TT), dim3(256), 0, stream,
                       X, Wg, bg, out);
}